// Round 2
// baseline (696.600 us; speedup 1.0000x reference)
//
#include <hip/hip_runtime.h>
#include <stdint.h>

#define B_   4
#define S_   2048
#define D_   1024
#define F_   4096
#define E_   8
#define KSEL 512

typedef __attribute__((ext_vector_type(8))) short short8;
typedef __attribute__((ext_vector_type(4))) float floatx4;

__device__ __forceinline__ unsigned short f2bf(float f) {
    unsigned u = __float_as_uint(f);
    unsigned r = (u + 0x7FFFu + ((u >> 16) & 1u)) >> 16;   // RNE
    return (unsigned short)r;
}

__device__ __forceinline__ void gload16(const void* g, void* l) {
    __builtin_amdgcn_global_load_lds(
        (const __attribute__((address_space(1))) void*)g,
        (__attribute__((address_space(3))) void*)l, 16, 0, 0);
}

__device__ __forceinline__ void barw()     { asm volatile("s_barrier" ::: "memory"); }
__device__ __forceinline__ void wait_vm8() { asm volatile("s_waitcnt vmcnt(8)" ::: "memory"); }
__device__ __forceinline__ void wait_vm0() { asm volatile("s_waitcnt vmcnt(0)" ::: "memory"); }

// ---------------------------------------------------------------- converts
__global__ void convert_kernel(const float* __restrict__ src,
                               unsigned short* __restrict__ dst, int n4) {
    int i = blockIdx.x * blockDim.x + threadIdx.x;
    int stride = gridDim.x * blockDim.x;
    const float4* s4 = (const float4*)src;
    ushort4* d4 = (ushort4*)dst;
    for (; i < n4; i += stride) {
        float4 v = s4[i];
        ushort4 o;
        o.x = f2bf(v.x); o.y = f2bf(v.y); o.z = f2bf(v.z); o.w = f2bf(v.w);
        d4[i] = o;
    }
}

// ---------------------------------------------------------------- router (+ x->bf16 fused)
__global__ void router_kernel(const float* __restrict__ x,
                              const float* __restrict__ choice,
                              float* __restrict__ probs,
                              unsigned short* __restrict__ xb) {
    int bs = blockIdx.x;               // 0..8191
    int b = bs >> 11, s = bs & 2047;
    int tid = threadIdx.x;
    const float4* xr = (const float4*)(x + (size_t)bs * D_);
    float4 xv = xr[tid];
    ushort4 o;
    o.x = f2bf(xv.x); o.y = f2bf(xv.y); o.z = f2bf(xv.z); o.w = f2bf(xv.w);
    ((ushort4*)(xb + (size_t)bs * D_))[tid] = o;

    float acc[E_];
#pragma unroll
    for (int e = 0; e < E_; e++) {
        const float4* cr = (const float4*)(choice + e * D_);
        float4 cv = cr[tid];
        acc[e] = xv.x * cv.x + xv.y * cv.y + xv.z * cv.z + xv.w * cv.w;
    }
    __shared__ float red[E_][4];
    int lane = tid & 63, w = tid >> 6;
#pragma unroll
    for (int e = 0; e < E_; e++) {
        float v = acc[e];
        for (int off = 32; off; off >>= 1) v += __shfl_down(v, off, 64);
        if (lane == 0) red[e][w] = v;
    }
    __syncthreads();
    if (tid == 0) {
        float l[E_], m = -1e30f;
#pragma unroll
        for (int e = 0; e < E_; e++) {
            l[e] = red[e][0] + red[e][1] + red[e][2] + red[e][3];
            m = fmaxf(m, l[e]);
        }
        float sum = 0.f, p[E_];
#pragma unroll
        for (int e = 0; e < E_; e++) { p[e] = __expf(l[e] - m); sum += p[e]; }
        float inv = 1.0f / sum;
#pragma unroll
        for (int e = 0; e < E_; e++)
            probs[((size_t)b * E_ + e) * S_ + s] = p[e] * inv;
    }
}

// ---------------------------------------------------------------- top-k by rank
__global__ void topk_kernel(const float* __restrict__ probs,
                            int* __restrict__ idxb, float* __restrict__ gateb) {
    __shared__ float ps[S_];
    int be = blockIdx.x >> 3;          // 0..31  (b*8+e)
    int chunk = blockIdx.x & 7;
    const float* p = probs + (size_t)be * S_;
    for (int i = threadIdx.x; i < S_; i += 256) ps[i] = p[i];
    __syncthreads();
    int t = chunk * 256 + threadIdx.x;
    float pt = ps[t];
    int rank = 0;
    for (int s = 0; s < S_; s++) {
        float v = ps[s];
        rank += (v > pt) || (v == pt && s < t);
    }
    if (rank < KSEL) {
        idxb[be * KSEL + rank] = t;
        gateb[be * KSEL + rank] = pt;
    }
}

// ---------------------------------------------------------------- 8-phase 256x256 BK=64 core
// LDS per buffer: A[256][64] bf16 @ 0, B[256][64] bf16 @ 32768; 2 buffers = 128 KiB.
// Swizzle: LDS(row, chunk) holds global chunk ^ (row&7)  (chunk = 16B unit, 8 per 128B row).
// Stage granularity: 4 quarter-tiles per K-tile, aligned with the phase read sets:
//   A_q0 = rows {0-63,128-191} (read P1), A_q1 = rows {64-127,192-255} (read P3)
//   B_q0 = cols {wn*64+[0,32)} (read P1),  B_q1 = cols {wn*64+32+[0,32)} (read P2)
// Per iter kt: P2 stages A_q0(kt+2), P3 B_q0(kt+2), P4 B_q1+A_q1(kt+2); vmcnt(8) at P4
// guarantees all of kt+1 landed (this iter's 8 loads are the only ones allowed in flight).
template<int MH, int NH>
__device__ __forceinline__ void mfma_quad(const short8 (&af)[4][2], const short8 (&bf)[2][2],
                                          floatx4 (&acc)[8][4]) {
#pragma unroll
    for (int ks = 0; ks < 2; ++ks)
#pragma unroll
        for (int m2 = 0; m2 < 4; ++m2)
#pragma unroll
            for (int n2 = 0; n2 < 2; ++n2)
                acc[MH*4+m2][NH*2+n2] = __builtin_amdgcn_mfma_f32_16x16x32_bf16(
                    af[m2][ks], bf[n2][ks], acc[MH*4+m2][NH*2+n2], 0, 0, 0);
}

template<int NK>
__device__ __forceinline__ void mm_core(const char* const aS[4], const char* const bS[4],
                                        char* smem, int tid, floatx4 (&acc)[8][4]) {
    const int lane = tid & 63;
    const int wid  = tid >> 6;
    const int wm   = wid >> 2;           // 2 M-warps
    const int wn   = wid & 3;            // 4 N-warps
    const int mrow = lane & 15;
    const int hi   = lane >> 4;
    const int sw0  = (hi ^ (mrow & 7)) << 4;          // ks=0 chunk
    const int sw1  = ((hi + 4) ^ (mrow & 7)) << 4;    // ks=1 chunk
    const int arow = (wm * 128 + mrow) * 128;
    const int brow = 32768 + (wn * 64 + mrow) * 128;

    int dstA[4], dstB[4];
#pragma unroll
    for (int q = 0; q < 2; ++q)
#pragma unroll
        for (int r = 0; r < 2; ++r) {
            dstA[q*2+r] = q * 8192 + r * 16384 + tid * 16;
            dstB[q*2+r] = 32768 + ((tid >> 8) + 2*r) * 8192 + q * 4096 + (tid & 255) * 16;
        }

    short8 af[4][2], bf0[2][2], bf1[2][2];

#define STG_A(P,Q,K) { gload16(aS[(Q)*2+0] + (size_t)(K)*128, smem + (P)*65536 + dstA[(Q)*2+0]); \
                       gload16(aS[(Q)*2+1] + (size_t)(K)*128, smem + (P)*65536 + dstA[(Q)*2+1]); }
#define STG_B(P,Q,K) { gload16(bS[(Q)*2+0] + (size_t)(K)*128, smem + (P)*65536 + dstB[(Q)*2+0]); \
                       gload16(bS[(Q)*2+1] + (size_t)(K)*128, smem + (P)*65536 + dstB[(Q)*2+1]); }

    // prologue: K-tile 0 -> buf0, K-tile 1 -> buf1; force k0 done, keep k1 in flight
    STG_A(0,0,0); STG_B(0,0,0); STG_B(0,1,0); STG_A(0,1,0);
    STG_A(1,0,1); STG_B(1,0,1); STG_B(1,1,1); STG_A(1,1,1);
    wait_vm8();
    barw();

    for (int kt = 0; kt < NK; ++kt) {
        const int p  = kt & 1;
        const int k2 = (kt + 2) & (NK - 1);   // wrapped: junk stages land in freed slots, never read
        const char* bA = smem + p * 65536;

        // ---- P1: read af(mh=0) + bf0; MFMA q(0,0)
#pragma unroll
        for (int m2 = 0; m2 < 4; ++m2) {
            const char* rb = bA + arow + m2 * 2048;
            af[m2][0] = *(const short8*)(rb + sw0);
            af[m2][1] = *(const short8*)(rb + sw1);
        }
#pragma unroll
        for (int n2 = 0; n2 < 2; ++n2) {
            const char* rb = bA + brow + n2 * 2048;
            bf0[n2][0] = *(const short8*)(rb + sw0);
            bf0[n2][1] = *(const short8*)(rb + sw1);
        }
        barw();
        __builtin_amdgcn_s_setprio(1);
        mfma_quad<0,0>(af, bf0, acc);
        __builtin_amdgcn_s_setprio(0);
        barw();

        // ---- P2: read bf1; stage A_q0(k2); MFMA q(0,1)
#pragma unroll
        for (int n2 = 0; n2 < 2; ++n2) {
            const char* rb = bA + brow + (2 + n2) * 2048;
            bf1[n2][0] = *(const short8*)(rb + sw0);
            bf1[n2][1] = *(const short8*)(rb + sw1);
        }
        STG_A(p, 0, k2);
        barw();
        __builtin_amdgcn_s_setprio(1);
        mfma_quad<0,1>(af, bf1, acc);
        __builtin_amdgcn_s_setprio(0);
        barw();

        // ---- P3: read af(mh=1); stage B_q0(k2); MFMA q(1,1)
#pragma unroll
        for (int m2 = 0; m2 < 4; ++m2) {
            const char* rb = bA + arow + (4 + m2) * 2048;
            af[m2][0] = *(const short8*)(rb + sw0);
            af[m2][1] = *(const short8*)(rb + sw1);
        }
        STG_B(p, 0, k2);
        barw();
        __builtin_amdgcn_s_setprio(1);
        mfma_quad<1,1>(af, bf1, acc);
        __builtin_amdgcn_s_setprio(0);
        barw();

        // ---- P4: stage B_q1(k2)+A_q1(k2); counted vmcnt; MFMA q(1,0)
        STG_B(p, 1, k2);
        STG_A(p, 1, k2);
        wait_vm8();
        barw();
        __builtin_amdgcn_s_setprio(1);
        mfma_quad<1,0>(af, bf0, acc);
        __builtin_amdgcn_s_setprio(0);
        barw();
    }
    wait_vm0();   // drain wrapped junk stages before LDS dealloc
#undef STG_A
#undef STG_B
}

// ---------------------------------------------------------------- GEMM1 + SiLU (256x256)
__global__ __launch_bounds__(512) void gemm1_8ph(
    const unsigned short* __restrict__ xb, const unsigned short* __restrict__ w1b,
    const int* __restrict__ idxb, unsigned short* __restrict__ hbuf) {
    extern __shared__ __align__(16) char smem[];
    const int tid = threadIdx.x;
    const int blk = blockIdx.x;            // 0..1023
    const int e  = blk & 7;                // XCD id
    const int q  = blk >> 3;               // 0..127
    const int b  = q >> 5;
    const int tm = (q >> 4) & 1;
    const int tn = q & 15;
    const int g  = b * 8 + e;

    const int t8   = tid >> 3;
    const int cswz = ((tid & 7) ^ (t8 & 7)) << 4;

    const char* aS[4]; const char* bS[4];
    {
        const int ar[4] = { t8, 128 + t8, 64 + t8, 192 + t8 };   // [q*2+r]
#pragma unroll
        for (int i = 0; i < 4; ++i) {
            int tok = idxb[g * KSEL + tm * 256 + ar[i]];
            aS[i] = (const char*)xb + ((size_t)(b * S_ + tok) * D_) * 2 + cswz;
        }
        const int u = tid >> 8, v = t8 & 31;
#pragma unroll
        for (int qq = 0; qq < 2; ++qq)
#pragma unroll
            for (int r = 0; r < 2; ++r) {
                int rowb = (u + 2*r) * 64 + qq * 32 + v;
                bS[qq*2+r] = (const char*)w1b + ((size_t)(e * F_ + tn * 256 + rowb) * D_) * 2 + cswz;
            }
    }

    floatx4 acc[8][4];
#pragma unroll
    for (int m = 0; m < 8; ++m)
#pragma unroll
        for (int n = 0; n < 4; ++n) acc[m][n] = (floatx4){0.f, 0.f, 0.f, 0.f};

    mm_core<D_ / 64>(aS, bS, smem, tid, acc);   // NK = 16

    const int lane = tid & 63, wid = tid >> 6;
    const int wm = wid >> 2, wn = wid & 3;
    const int mrow = lane & 15, hi = lane >> 4;
    unsigned short* hr = hbuf + (size_t)g * ((size_t)KSEL * F_);
#pragma unroll
    for (int m = 0; m < 8; ++m) {
#pragma unroll
        for (int r2 = 0; r2 < 4; ++r2) {
            const int rowc = tm*256 + wm*128 + m*16 + hi*4 + r2;
            unsigned short* hrow = hr + (size_t)rowc * F_ + tn*256 + wn*64 + mrow;
#pragma unroll
            for (int n = 0; n < 4; ++n) {
                float v = acc[m][n][r2];
                float s = v / (1.0f + __expf(-v));
                hrow[n * 16] = f2bf(s);
            }
        }
    }
}

// ---------------------------------------------------------------- GEMM2 + gate*scatter (256x256, no split-K)
__global__ __launch_bounds__(512) void gemm2_8ph(
    const unsigned short* __restrict__ hbuf, const unsigned short* __restrict__ w2b,
    const int* __restrict__ idxb, const float* __restrict__ gateb,
    float* __restrict__ out) {
    extern __shared__ __align__(16) char smem[];
    const int tid = threadIdx.x;
    const int blk = blockIdx.x;            // 0..255
    const int e  = blk & 7;
    const int q  = blk >> 3;               // 0..31
    const int b  = q >> 3;
    const int tm = (q >> 2) & 1;
    const int tn = q & 3;
    const int g  = b * 8 + e;

    const int t8   = tid >> 3;
    const int cswz = ((tid & 7) ^ (t8 & 7)) << 4;

    const char* aS[4]; const char* bS[4];
    {
        const int ar[4] = { t8, 128 + t8, 64 + t8, 192 + t8 };
#pragma unroll
        for (int i = 0; i < 4; ++i)
            aS[i] = (const char*)hbuf + ((size_t)(g * KSEL + tm * 256 + ar[i]) * F_) * 2 + cswz;
        const int u = tid >> 8, v = t8 & 31;
#pragma unroll
        for (int qq = 0; qq < 2; ++qq)
#pragma unroll
            for (int r = 0; r < 2; ++r) {
                int rowb = (u + 2*r) * 64 + qq * 32 + v;
                bS[qq*2+r] = (const char*)w2b + ((size_t)(e * D_ + tn * 256 + rowb) * F_) * 2 + cswz;
            }
    }

    floatx4 acc[8][4];
#pragma unroll
    for (int m = 0; m < 8; ++m)
#pragma unroll
        for (int n = 0; n < 4; ++n) acc[m][n] = (floatx4){0.f, 0.f, 0.f, 0.f};

    mm_core<F_ / 64>(aS, bS, smem, tid, acc);   // NK = 64

    const int lane = tid & 63, wid = tid >> 6;
    const int wm = wid >> 2, wn = wid & 3;
    const int mrow = lane & 15, hi = lane >> 4;
#pragma unroll
    for (int m = 0; m < 8; ++m) {
#pragma unroll
        for (int r2 = 0; r2 < 4; ++r2) {
            const int slot = tm*256 + wm*128 + m*16 + hi*4 + r2;
            const int tok  = idxb[g * KSEL + slot];
            const float gt = gateb[g * KSEL + slot];
            float* orow = out + ((size_t)b * S_ + tok) * D_ + tn*256 + wn*64 + mrow;
#pragma unroll
            for (int n = 0; n < 4; ++n)
                atomicAdd(&orow[n * 16], gt * acc[m][n][r2]);
        }
    }
}

// ---------------------------------------------------------------- launch
extern "C" void kernel_launch(void* const* d_in, const int* in_sizes, int n_in,
                              void* d_out, int out_size, void* d_ws, size_t ws_size,
                              hipStream_t stream) {
    const float* x      = (const float*)d_in[0];
    const float* choice = (const float*)d_in[1];
    const float* w1     = (const float*)d_in[2];
    const float* w2     = (const float*)d_in[3];
    float* out = (float*)d_out;
    char* ws = (char*)d_ws;

    static bool inited = false;
    if (!inited) {
        hipFuncSetAttribute(reinterpret_cast<const void*>(&gemm1_8ph),
                            hipFuncAttributeMaxDynamicSharedMemorySize, 131072);
        hipFuncSetAttribute(reinterpret_cast<const void*>(&gemm2_8ph),
                            hipFuncAttributeMaxDynamicSharedMemorySize, 131072);
        inited = true;
    }

    // workspace layout (bytes)
    unsigned short* w1b = (unsigned short*)(ws);                  // 67,108,864
    unsigned short* w2b = (unsigned short*)(ws + 67108864);       // 67,108,864
    unsigned short* xb  = (unsigned short*)(ws + 134217728);      // 16,777,216
    unsigned short* hb  = (unsigned short*)(ws + 150994944);      // 134,217,728
    float* probs        = (float*)(ws + 285212672);               // 262,144
    int*   idxb         = (int*)(ws + 285474816);                 // 65,536
    float* gateb        = (float*)(ws + 285540352);               // 65,536

    hipMemsetAsync(d_out, 0, (size_t)out_size * sizeof(float), stream);
    convert_kernel<<<8192, 256, 0, stream>>>(w1, w1b, 8388608);
    convert_kernel<<<8192, 256, 0, stream>>>(w2, w2b, 8388608);
    router_kernel<<<B_ * S_, 256, 0, stream>>>(x, choice, probs, xb);
    topk_kernel<<<B_ * E_ * 8, 256, 0, stream>>>(probs, idxb, gateb);
    gemm1_8ph<<<1024, 512, 131072, stream>>>(xb, w1b, idxb, hb);
    gemm2_8ph<<<256, 512, 131072, stream>>>(hb, w2b, idxb, gateb, out);
}

// Round 13
// 662.131 us; speedup vs baseline: 1.0521x; 1.0521x over previous
//
#include <hip/hip_runtime.h>
#include <stdint.h>

#define B_   4
#define S_   2048
#define D_   1024
#define F_   4096
#define E_   8
#define KSEL 512

typedef __attribute__((ext_vector_type(8))) short short8;
typedef __attribute__((ext_vector_type(4))) float floatx4;

__device__ __forceinline__ unsigned short f2bf(float f) {
    unsigned u = __float_as_uint(f);
    unsigned r = (u + 0x7FFFu + ((u >> 16) & 1u)) >> 16;   // RNE
    return (unsigned short)r;
}

__device__ __forceinline__ void gload16(const void* g, void* l) {
    __builtin_amdgcn_global_load_lds(
        (const __attribute__((address_space(1))) void*)g,
        (__attribute__((address_space(3))) void*)l, 16, 0, 0);
}

__device__ __forceinline__ void barw()     { asm volatile("s_barrier" ::: "memory"); }
__device__ __forceinline__ void wait_vm8() { asm volatile("s_waitcnt vmcnt(8)" ::: "memory"); }
__device__ __forceinline__ void wait_vm0() { asm volatile("s_waitcnt vmcnt(0)" ::: "memory"); }

// ---------------------------------------------------------------- converts (both weights, one launch)
__global__ void convert2_kernel(const float* __restrict__ s0, unsigned short* __restrict__ d0,
                                const float* __restrict__ s1, unsigned short* __restrict__ d1,
                                int n4) {
    int i = blockIdx.x * blockDim.x + threadIdx.x;
    int stride = gridDim.x * blockDim.x;
    for (; i < 2 * n4; i += stride) {
        const int sel = i < n4;
        const float4* s4 = (const float4*)(sel ? s0 : s1);
        ushort4* d4 = (ushort4*)(sel ? d0 : d1);
        const int j = sel ? i : i - n4;
        float4 v = s4[j];
        ushort4 o;
        o.x = f2bf(v.x); o.y = f2bf(v.y); o.z = f2bf(v.z); o.w = f2bf(v.w);
        d4[j] = o;
    }
}

// ---------------------------------------------------------------- router (+ x->bf16 fused, + cnt zero)
__global__ void router_kernel(const float* __restrict__ x,
                              const float* __restrict__ choice,
                              float* __restrict__ probs,
                              unsigned short* __restrict__ xb,
                              int* __restrict__ cnt) {
    int bs = blockIdx.x;               // 0..8191
    int b = bs >> 11, s = bs & 2047;
    int tid = threadIdx.x;
    const float4* xr = (const float4*)(x + (size_t)bs * D_);
    float4 xv = xr[tid];
    ushort4 o;
    o.x = f2bf(xv.x); o.y = f2bf(xv.y); o.z = f2bf(xv.z); o.w = f2bf(xv.w);
    ((ushort4*)(xb + (size_t)bs * D_))[tid] = o;

    float acc[E_];
#pragma unroll
    for (int e = 0; e < E_; e++) {
        const float4* cr = (const float4*)(choice + e * D_);
        float4 cv = cr[tid];
        acc[e] = xv.x * cv.x + xv.y * cv.y + xv.z * cv.z + xv.w * cv.w;
    }
    __shared__ float red[E_][4];
    int lane = tid & 63, w = tid >> 6;
#pragma unroll
    for (int e = 0; e < E_; e++) {
        float v = acc[e];
        for (int off = 32; off; off >>= 1) v += __shfl_down(v, off, 64);
        if (lane == 0) red[e][w] = v;
    }
    __syncthreads();
    if (tid == 0) {
        cnt[bs] = 0;                   // zero inverse-map counter (replaces hipMemsetAsync)
        float l[E_], m = -1e30f;
#pragma unroll
        for (int e = 0; e < E_; e++) {
            l[e] = red[e][0] + red[e][1] + red[e][2] + red[e][3];
            m = fmaxf(m, l[e]);
        }
        float sum = 0.f, p[E_];
#pragma unroll
        for (int e = 0; e < E_; e++) { p[e] = __expf(l[e] - m); sum += p[e]; }
        float inv = 1.0f / sum;
#pragma unroll
        for (int e = 0; e < E_; e++)
            probs[((size_t)b * E_ + e) * S_ + s] = p[e] * inv;
    }
}

// ---------------------------------------------------------------- top-k by rank (+ inverse map)
__global__ void topk_kernel(const float* __restrict__ probs,
                            int* __restrict__ idxb, float* __restrict__ gateb,
                            int* __restrict__ cnt, int* __restrict__ lst) {
    __shared__ float ps[S_];
    int be = blockIdx.x >> 3;          // 0..31  (b*8+e)
    int chunk = blockIdx.x & 7;
    const float* p = probs + (size_t)be * S_;
    for (int i = threadIdx.x; i < S_; i += 256) ps[i] = p[i];
    __syncthreads();
    int t = chunk * 256 + threadIdx.x;
    float pt = ps[t];
    int rank = 0;
    for (int s = 0; s < S_; s++) {
        float v = ps[s];
        rank += (v > pt) || (v == pt && s < t);
    }
    if (rank < KSEL) {
        idxb[be * KSEL + rank] = t;
        gateb[be * KSEL + rank] = pt;
        int b = be >> 3;
        int pos = atomicAdd(&cnt[b * S_ + t], 1);      // <=8 entries per (b,t)
        lst[(b * S_ + t) * 8 + pos] = be * KSEL + rank;
    }
}

// ---------------------------------------------------------------- 8-phase 256x256 BK=64 core
// LDS per buffer: A[256][64] bf16 @ 0, B[256][64] bf16 @ 32768; 2 buffers = 128 KiB.
// Swizzle: LDS(row, chunk) holds global chunk ^ (row&7)  (chunk = 16B unit, 8 per 128B row).
template<int MH, int NH>
__device__ __forceinline__ void mfma_quad(const short8 (&af)[4][2], const short8 (&bf)[2][2],
                                          floatx4 (&acc)[8][4]) {
#pragma unroll
    for (int ks = 0; ks < 2; ++ks)
#pragma unroll
        for (int m2 = 0; m2 < 4; ++m2)
#pragma unroll
            for (int n2 = 0; n2 < 2; ++n2)
                acc[MH*4+m2][NH*2+n2] = __builtin_amdgcn_mfma_f32_16x16x32_bf16(
                    af[m2][ks], bf[n2][ks], acc[MH*4+m2][NH*2+n2], 0, 0, 0);
}

template<int NK>
__device__ __forceinline__ void mm_core(const char* const aS[4], const char* const bS[4],
                                        char* smem, int tid, floatx4 (&acc)[8][4]) {
    const int lane = tid & 63;
    const int wid  = tid >> 6;
    const int wm   = wid >> 2;           // 2 M-warps
    const int wn   = wid & 3;            // 4 N-warps
    const int mrow = lane & 15;
    const int hi   = lane >> 4;
    const int sw0  = (hi ^ (mrow & 7)) << 4;          // ks=0 chunk
    const int sw1  = ((hi + 4) ^ (mrow & 7)) << 4;    // ks=1 chunk
    const int arow = (wm * 128 + mrow) * 128;
    const int brow = 32768 + (wn * 64 + mrow) * 128;

    int dstA[4], dstB[4];
#pragma unroll
    for (int q = 0; q < 2; ++q)
#pragma unroll
        for (int r = 0; r < 2; ++r) {
            dstA[q*2+r] = q * 8192 + r * 16384 + tid * 16;
            dstB[q*2+r] = 32768 + ((tid >> 8) + 2*r) * 8192 + q * 4096 + (tid & 255) * 16;
        }

    short8 af[4][2], bf0[2][2], bf1[2][2];

#define STG_A(P,Q,K) { gload16(aS[(Q)*2+0] + (size_t)(K)*128, smem + (P)*65536 + dstA[(Q)*2+0]); \
                       gload16(aS[(Q)*2+1] + (size_t)(K)*128, smem + (P)*65536 + dstA[(Q)*2+1]); }
#define STG_B(P,Q,K) { gload16(bS[(Q)*2+0] + (size_t)(K)*128, smem + (P)*65536 + dstB[(Q)*2+0]); \
                       gload16(bS[(Q)*2+1] + (size_t)(K)*128, smem + (P)*65536 + dstB[(Q)*2+1]); }

    // prologue: K-tile 0 -> buf0, K-tile 1 -> buf1; force k0 done, keep k1 in flight
    STG_A(0,0,0); STG_B(0,0,0); STG_B(0,1,0); STG_A(0,1,0);
    STG_A(1,0,1); STG_B(1,0,1); STG_B(1,1,1); STG_A(1,1,1);
    wait_vm8();
    barw();

    for (int kt = 0; kt < NK; ++kt) {
        const int p  = kt & 1;
        const int k2 = (kt + 2) & (NK - 1);   // wrapped: junk stages land in freed slots, never read
        const char* bA = smem + p * 65536;

        // ---- P1: read af(mh=0) + bf0; MFMA q(0,0)
#pragma unroll
        for (int m2 = 0; m2 < 4; ++m2) {
            const char* rb = bA + arow + m2 * 2048;
            af[m2][0] = *(const short8*)(rb + sw0);
            af[m2][1] = *(const short8*)(rb + sw1);
        }
#pragma unroll
        for (int n2 = 0; n2 < 2; ++n2) {
            const char* rb = bA + brow + n2 * 2048;
            bf0[n2][0] = *(const short8*)(rb + sw0);
            bf0[n2][1] = *(const short8*)(rb + sw1);
        }
        barw();
        __builtin_amdgcn_s_setprio(1);
        mfma_quad<0,0>(af, bf0, acc);
        __builtin_amdgcn_s_setprio(0);
        barw();

        // ---- P2: read bf1; stage A_q0(k2); MFMA q(0,1)
#pragma unroll
        for (int n2 = 0; n2 < 2; ++n2) {
            const char* rb = bA + brow + (2 + n2) * 2048;
            bf1[n2][0] = *(const short8*)(rb + sw0);
            bf1[n2][1] = *(const short8*)(rb + sw1);
        }
        STG_A(p, 0, k2);
        barw();
        __builtin_amdgcn_s_setprio(1);
        mfma_quad<0,1>(af, bf1, acc);
        __builtin_amdgcn_s_setprio(0);
        barw();

        // ---- P3: read af(mh=1); stage B_q0(k2); MFMA q(1,1)
#pragma unroll
        for (int m2 = 0; m2 < 4; ++m2) {
            const char* rb = bA + arow + (4 + m2) * 2048;
            af[m2][0] = *(const short8*)(rb + sw0);
            af[m2][1] = *(const short8*)(rb + sw1);
        }
        STG_B(p, 0, k2);
        barw();
        __builtin_amdgcn_s_setprio(1);
        mfma_quad<1,1>(af, bf1, acc);
        __builtin_amdgcn_s_setprio(0);
        barw();

        // ---- P4: stage B_q1(k2)+A_q1(k2); counted vmcnt; MFMA q(1,0)
        STG_B(p, 1, k2);
        STG_A(p, 1, k2);
        wait_vm8();
        barw();
        __builtin_amdgcn_s_setprio(1);
        mfma_quad<1,0>(af, bf0, acc);
        __builtin_amdgcn_s_setprio(0);
        barw();
    }
    wait_vm0();   // drain wrapped junk stages before LDS dealloc
#undef STG_A
#undef STG_B
}

// ---------------------------------------------------------------- GEMM1 + SiLU (256x256)
__global__ __launch_bounds__(512) void gemm1_8ph(
    const unsigned short* __restrict__ xb, const unsigned short* __restrict__ w1b,
    const int* __restrict__ idxb, unsigned short* __restrict__ hbuf) {
    extern __shared__ __align__(16) char smem[];
    const int tid = threadIdx.x;
    const int blk = blockIdx.x;            // 0..1023
    const int e  = blk & 7;                // XCD id
    const int q  = blk >> 3;               // 0..127
    const int b  = q >> 5;
    const int tm = (q >> 4) & 1;
    const int tn = q & 15;
    const int g  = b * 8 + e;

    const int t8   = tid >> 3;
    const int cswz = ((tid & 7) ^ (t8 & 7)) << 4;

    const char* aS[4]; const char* bS[4];
    {
        const int ar[4] = { t8, 128 + t8, 64 + t8, 192 + t8 };   // [q*2+r]
#pragma unroll
        for (int i = 0; i < 4; ++i) {
            int tok = idxb[g * KSEL + tm * 256 + ar[i]];
            aS[i] = (const char*)xb + ((size_t)(b * S_ + tok) * D_) * 2 + cswz;
        }
        const int u = tid >> 8, v = t8 & 31;
#pragma unroll
        for (int qq = 0; qq < 2; ++qq)
#pragma unroll
            for (int r = 0; r < 2; ++r) {
                int rowb = (u + 2*r) * 64 + qq * 32 + v;
                bS[qq*2+r] = (const char*)w1b + ((size_t)(e * F_ + tn * 256 + rowb) * D_) * 2 + cswz;
            }
    }

    floatx4 acc[8][4];
#pragma unroll
    for (int m = 0; m < 8; ++m)
#pragma unroll
        for (int n = 0; n < 4; ++n) acc[m][n] = (floatx4){0.f, 0.f, 0.f, 0.f};

    mm_core<D_ / 64>(aS, bS, smem, tid, acc);   // NK = 16

    const int lane = tid & 63, wid = tid >> 6;
    const int wm = wid >> 2, wn = wid & 3;
    const int mrow = lane & 15, hi = lane >> 4;
    unsigned short* hr = hbuf + (size_t)g * ((size_t)KSEL * F_);
#pragma unroll
    for (int m = 0; m < 8; ++m) {
#pragma unroll
        for (int r2 = 0; r2 < 4; ++r2) {
            const int rowc = tm*256 + wm*128 + m*16 + hi*4 + r2;
            unsigned short* hrow = hr + (size_t)rowc * F_ + tn*256 + wn*64 + mrow;
#pragma unroll
            for (int n = 0; n < 4; ++n) {
                float v = acc[m][n][r2];
                float s = v / (1.0f + __expf(-v));
                hrow[n * 16] = f2bf(s);
            }
        }
    }
}

// ---------------------------------------------------------------- GEMM2 + gated coalesced store (256x256)
__global__ __launch_bounds__(512) void gemm2_8ph(
    const unsigned short* __restrict__ hbuf, const unsigned short* __restrict__ w2b,
    const float* __restrict__ gateb, float* __restrict__ cmb) {
    extern __shared__ __align__(16) char smem[];
    const int tid = threadIdx.x;
    const int blk = blockIdx.x;            // 0..255
    const int e  = blk & 7;
    const int q  = blk >> 3;               // 0..31
    const int b  = q >> 3;
    const int tm = (q >> 2) & 1;
    const int tn = q & 3;
    const int g  = b * 8 + e;

    const int t8   = tid >> 3;
    const int cswz = ((tid & 7) ^ (t8 & 7)) << 4;

    const char* aS[4]; const char* bS[4];
    {
        const int ar[4] = { t8, 128 + t8, 64 + t8, 192 + t8 };
#pragma unroll
        for (int i = 0; i < 4; ++i)
            aS[i] = (const char*)hbuf + ((size_t)(g * KSEL + tm * 256 + ar[i]) * F_) * 2 + cswz;
        const int u = tid >> 8, v = t8 & 31;
#pragma unroll
        for (int qq = 0; qq < 2; ++qq)
#pragma unroll
            for (int r = 0; r < 2; ++r) {
                int rowb = (u + 2*r) * 64 + qq * 32 + v;
                bS[qq*2+r] = (const char*)w2b + ((size_t)(e * D_ + tn * 256 + rowb) * F_) * 2 + cswz;
            }
    }

    floatx4 acc[8][4];
#pragma unroll
    for (int m = 0; m < 8; ++m)
#pragma unroll
        for (int n = 0; n < 4; ++n) acc[m][n] = (floatx4){0.f, 0.f, 0.f, 0.f};

    mm_core<F_ / 64>(aS, bS, smem, tid, acc);   // NK = 64

    const int lane = tid & 63, wid = tid >> 6;
    const int wm = wid >> 2, wn = wid & 3;
    const int mrow = lane & 15, hi = lane >> 4;
#pragma unroll
    for (int m = 0; m < 8; ++m) {
#pragma unroll
        for (int r2 = 0; r2 < 4; ++r2) {
            const int slot = tm*256 + wm*128 + m*16 + hi*4 + r2;
            const float gt = gateb[g * KSEL + slot];
            float* crow = cmb + ((size_t)g * KSEL + slot) * D_ + tn*256 + wn*64 + mrow;
#pragma unroll
            for (int n = 0; n < 4; ++n)
                crow[n * 16] = gt * acc[m][n][r2];
        }
    }
}

// ---------------------------------------------------------------- combine: out[b,s,:] = sum over selecting experts
__global__ void combine_kernel(const float* __restrict__ cmb,
                               const int* __restrict__ cnt,
                               const int* __restrict__ lst,
                               float* __restrict__ out) {
    const int bs = blockIdx.x;          // 0..8191  (b*S+s)
    const int tid = threadIdx.x;        // 256, float4 each -> D=1024
    const int c = cnt[bs];
    float4 acc = {0.f, 0.f, 0.f, 0.f};
    for (int i = 0; i < c; ++i) {
        const int idx = lst[bs * 8 + i];              // g*KSEL+slot
        const float4 v = ((const float4*)(cmb + (size_t)idx * D_))[tid];
        acc.x += v.x; acc.y += v.y; acc.z += v.z; acc.w += v.w;
    }
    ((float4*)(out + (size_t)bs * D_))[tid] = acc;
}

// ---------------------------------------------------------------- launch
extern "C" void kernel_launch(void* const* d_in, const int* in_sizes, int n_in,
                              void* d_out, int out_size, void* d_ws, size_t ws_size,
                              hipStream_t stream) {
    const float* x      = (const float*)d_in[0];
    const float* choice = (const float*)d_in[1];
    const float* w1     = (const float*)d_in[2];
    const float* w2     = (const float*)d_in[3];
    float* out = (float*)d_out;
    char* ws = (char*)d_ws;

    static bool inited = false;
    if (!inited) {
        hipFuncSetAttribute(reinterpret_cast<const void*>(&gemm1_8ph),
                            hipFuncAttributeMaxDynamicSharedMemorySize, 131072);
        hipFuncSetAttribute(reinterpret_cast<const void*>(&gemm2_8ph),
                            hipFuncAttributeMaxDynamicSharedMemorySize, 131072);
        inited = true;
    }

    // workspace layout (bytes)
    unsigned short* w1b = (unsigned short*)(ws);                  // 67,108,864 (reused as cmb after gemm1)
    unsigned short* w2b = (unsigned short*)(ws + 67108864);       // 67,108,864
    unsigned short* xb  = (unsigned short*)(ws + 134217728);      // 16,777,216
    unsigned short* hb  = (unsigned short*)(ws + 150994944);      // 134,217,728
    float* probs        = (float*)(ws + 285212672);               // 262,144
    int*   idxb         = (int*)(ws + 285474816);                 // 65,536
    float* gateb        = (float*)(ws + 285540352);               // 65,536
    int*   cnt          = (int*)(ws + 285605888);                 // 32,768
    int*   lst          = (int*)(ws + 285638656);                 // 262,144
    float* cmb          = (float*)(ws);                           // overlays w1b (dead after gemm1)

    convert2_kernel<<<16384, 256, 0, stream>>>(w1, w1b, w2, w2b, 8388608);
    router_kernel<<<B_ * S_, 256, 0, stream>>>(x, choice, probs, xb, cnt);
    topk_kernel<<<B_ * E_ * 8, 256, 0, stream>>>(probs, idxb, gateb, cnt, lst);
    gemm1_8ph<<<1024, 512, 131072, stream>>>(xb, w1b, idxb, hb);
    gemm2_8ph<<<256, 512, 131072, stream>>>(hb, w2b, gateb, cmb);
    combine_kernel<<<B_ * S_, 256, 0, stream>>>(cmb, cnt, lst, out);
}

// Round 15
// 646.690 us; speedup vs baseline: 1.0772x; 1.0239x over previous
//
#include <hip/hip_runtime.h>
#include <stdint.h>

#define B_   4
#define S_   2048
#define D_   1024
#define F_   4096
#define E_   8
#define KSEL 512

typedef __attribute__((ext_vector_type(8))) short short8;
typedef __attribute__((ext_vector_type(4))) float floatx4;

__device__ __forceinline__ unsigned short f2bf(float f) {
    unsigned u = __float_as_uint(f);
    unsigned r = (u + 0x7FFFu + ((u >> 16) & 1u)) >> 16;   // RNE
    return (unsigned short)r;
}

__device__ __forceinline__ void gload16(const void* g, void* l) {
    __builtin_amdgcn_global_load_lds(
        (const __attribute__((address_space(1))) void*)g,
        (__attribute__((address_space(3))) void*)l, 16, 0, 0);
}

__device__ __forceinline__ void barw()     { asm volatile("s_barrier" ::: "memory"); }
__device__ __forceinline__ void wait_vm8() { asm volatile("s_waitcnt vmcnt(8)" ::: "memory"); }
__device__ __forceinline__ void wait_vm0() { asm volatile("s_waitcnt vmcnt(0)" ::: "memory"); }

// ---------------------------------------------------------------- converts (both weights, one launch)
__global__ void convert2_kernel(const float* __restrict__ s0, unsigned short* __restrict__ d0,
                                const float* __restrict__ s1, unsigned short* __restrict__ d1,
                                int n4) {
    int i = blockIdx.x * blockDim.x + threadIdx.x;
    int stride = gridDim.x * blockDim.x;
    for (; i < 2 * n4; i += stride) {
        const int sel = i < n4;
        const float4* s4 = (const float4*)(sel ? s0 : s1);
        ushort4* d4 = (ushort4*)(sel ? d0 : d1);
        const int j = sel ? i : i - n4;
        float4 v = s4[j];
        ushort4 o;
        o.x = f2bf(v.x); o.y = f2bf(v.y); o.z = f2bf(v.z); o.w = f2bf(v.w);
        d4[j] = o;
    }
}

// ---------------------------------------------------------------- router (+ x->bf16 fused, + cnt zero)
__global__ void router_kernel(const float* __restrict__ x,
                              const float* __restrict__ choice,
                              float* __restrict__ probs,
                              unsigned short* __restrict__ xb,
                              int* __restrict__ cnt) {
    int bs = blockIdx.x;               // 0..8191
    int b = bs >> 11, s = bs & 2047;
    int tid = threadIdx.x;
    const float4* xr = (const float4*)(x + (size_t)bs * D_);
    float4 xv = xr[tid];
    ushort4 o;
    o.x = f2bf(xv.x); o.y = f2bf(xv.y); o.z = f2bf(xv.z); o.w = f2bf(xv.w);
    ((ushort4*)(xb + (size_t)bs * D_))[tid] = o;

    float acc[E_];
#pragma unroll
    for (int e = 0; e < E_; e++) {
        const float4* cr = (const float4*)(choice + e * D_);
        float4 cv = cr[tid];
        acc[e] = xv.x * cv.x + xv.y * cv.y + xv.z * cv.z + xv.w * cv.w;
    }
    __shared__ float red[E_][4];
    int lane = tid & 63, w = tid >> 6;
#pragma unroll
    for (int e = 0; e < E_; e++) {
        float v = acc[e];
        for (int off = 32; off; off >>= 1) v += __shfl_down(v, off, 64);
        if (lane == 0) red[e][w] = v;
    }
    __syncthreads();
    if (tid == 0) {
        cnt[bs] = 0;                   // zero inverse-map counter (replaces hipMemsetAsync)
        float l[E_], m = -1e30f;
#pragma unroll
        for (int e = 0; e < E_; e++) {
            l[e] = red[e][0] + red[e][1] + red[e][2] + red[e][3];
            m = fmaxf(m, l[e]);
        }
        float sum = 0.f, p[E_];
#pragma unroll
        for (int e = 0; e < E_; e++) { p[e] = __expf(l[e] - m); sum += p[e]; }
        float inv = 1.0f / sum;
#pragma unroll
        for (int e = 0; e < E_; e++)
            probs[((size_t)b * E_ + e) * S_ + s] = p[e] * inv;
    }
}

// ---------------------------------------------------------------- top-k by rank (+ inverse map)
__global__ void topk_kernel(const float* __restrict__ probs,
                            int* __restrict__ idxb, float* __restrict__ gateb,
                            int* __restrict__ cnt, int* __restrict__ lst) {
    __shared__ float ps[S_];
    int be = blockIdx.x >> 3;          // 0..31  (b*8+e)
    int chunk = blockIdx.x & 7;
    const float* p = probs + (size_t)be * S_;
    for (int i = threadIdx.x; i < S_; i += 256) ps[i] = p[i];
    __syncthreads();
    int t = chunk * 256 + threadIdx.x;
    float pt = ps[t];
    int rank = 0;
    for (int s = 0; s < S_; s++) {
        float v = ps[s];
        rank += (v > pt) || (v == pt && s < t);
    }
    if (rank < KSEL) {
        idxb[be * KSEL + rank] = t;
        gateb[be * KSEL + rank] = pt;
        int b = be >> 3;
        int pos = atomicAdd(&cnt[b * S_ + t], 1);      // <=8 entries per (b,t)
        lst[(b * S_ + t) * 8 + pos] = be * KSEL + rank;
    }
}

// ---------------------------------------------------------------- 8-phase 256x256 BK=64 core
// LDS per buffer: A[256][64] bf16 @ 0, B[256][64] bf16 @ 32768; 2 buffers = 128 KiB.
// Swizzle: LDS(row, chunk) holds global chunk ^ (row&7)  (chunk = 16B unit, 8 per 128B row).
// Barrier schedule (6/K-tile): closing barriers after P2/P4 MFMA removed — provably safe:
//   a closing barrier is needed only if the NEXT phase stages rows read THIS phase.
//   P2 stages A_q0 (read P1, synced by P1-close); P3 stages B_q0 (read P1, synced by P1-close);
//   P4 stages B_q1 (read P2, synced by P3-pre chain) + A_q1 (read P3, synced by P3-close);
//   next-P1 reads other buffer (gated by P4-pre vmcnt+barrier). So P2/P4 MFMA may overlap
//   other waves' following reads — cross-wave read||MFMA overlap in 2 of 4 phases.
template<int MH, int NH>
__device__ __forceinline__ void mfma_quad(const short8 (&af)[4][2], const short8 (&bf)[2][2],
                                          floatx4 (&acc)[8][4]) {
#pragma unroll
    for (int m2 = 0; m2 < 4; ++m2)
#pragma unroll
        for (int n2 = 0; n2 < 2; ++n2)
#pragma unroll
            for (int ks = 0; ks < 2; ++ks)
                acc[MH*4+m2][NH*2+n2] = __builtin_amdgcn_mfma_f32_16x16x32_bf16(
                    af[m2][ks], bf[n2][ks], acc[MH*4+m2][NH*2+n2], 0, 0, 0);
}

template<int NK>
__device__ __forceinline__ void mm_core(const char* const aS[4], const char* const bS[4],
                                        char* smem, int tid, floatx4 (&acc)[8][4]) {
    const int lane = tid & 63;
    const int wid  = tid >> 6;
    const int wm   = wid >> 2;           // 2 M-warps
    const int wn   = wid & 3;            // 4 N-warps
    const int mrow = lane & 15;
    const int hi   = lane >> 4;
    const int sw0  = (hi ^ (mrow & 7)) << 4;          // ks=0 chunk
    const int sw1  = ((hi + 4) ^ (mrow & 7)) << 4;    // ks=1 chunk
    const int arow = (wm * 128 + mrow) * 128;
    const int brow = 32768 + (wn * 64 + mrow) * 128;

    int dstA[4], dstB[4];
#pragma unroll
    for (int q = 0; q < 2; ++q)
#pragma unroll
        for (int r = 0; r < 2; ++r) {
            dstA[q*2+r] = q * 8192 + r * 16384 + tid * 16;
            dstB[q*2+r] = 32768 + ((tid >> 8) + 2*r) * 8192 + q * 4096 + (tid & 255) * 16;
        }

    short8 af[4][2], bf0[2][2], bf1[2][2];

#define STG_A(P,Q,K) { gload16(aS[(Q)*2+0] + (size_t)(K)*128, smem + (P)*65536 + dstA[(Q)*2+0]); \
                       gload16(aS[(Q)*2+1] + (size_t)(K)*128, smem + (P)*65536 + dstA[(Q)*2+1]); }
#define STG_B(P,Q,K) { gload16(bS[(Q)*2+0] + (size_t)(K)*128, smem + (P)*65536 + dstB[(Q)*2+0]); \
                       gload16(bS[(Q)*2+1] + (size_t)(K)*128, smem + (P)*65536 + dstB[(Q)*2+1]); }

    // prologue: K-tile 0 -> buf0, K-tile 1 -> buf1; force k0 done, keep k1 in flight
    STG_A(0,0,0); STG_B(0,0,0); STG_B(0,1,0); STG_A(0,1,0);
    STG_A(1,0,1); STG_B(1,0,1); STG_B(1,1,1); STG_A(1,1,1);
    wait_vm8();
    barw();

    for (int kt = 0; kt < NK; ++kt) {
        const int p  = kt & 1;
        const int k2 = (kt + 2) & (NK - 1);   // wrapped: junk stages land in freed slots, never read
        const char* bA = smem + p * 65536;

        // ---- P1: reads interleaved so first MFMA operands land first
        {
            const char* rb = bA + arow;
            af[0][0] = *(const short8*)(rb + sw0);
            af[0][1] = *(const short8*)(rb + sw1);
        }
#pragma unroll
        for (int n2 = 0; n2 < 2; ++n2) {
            const char* rb = bA + brow + n2 * 2048;
            bf0[n2][0] = *(const short8*)(rb + sw0);
            bf0[n2][1] = *(const short8*)(rb + sw1);
        }
#pragma unroll
        for (int m2 = 1; m2 < 4; ++m2) {
            const char* rb = bA + arow + m2 * 2048;
            af[m2][0] = *(const short8*)(rb + sw0);
            af[m2][1] = *(const short8*)(rb + sw1);
        }
        barw();                                   // P1-pre
        __builtin_amdgcn_s_setprio(1);
        mfma_quad<0,0>(af, bf0, acc);
        __builtin_amdgcn_s_setprio(0);
        barw();                                   // P1-close (A_q0/B_q0 readers synced)

        // ---- P2: read bf1; stage A_q0(k2); MFMA q(0,1); NO closing barrier
#pragma unroll
        for (int n2 = 0; n2 < 2; ++n2) {
            const char* rb = bA + brow + (2 + n2) * 2048;
            bf1[n2][0] = *(const short8*)(rb + sw0);
            bf1[n2][1] = *(const short8*)(rb + sw1);
        }
        STG_A(p, 0, k2);
        barw();                                   // P2-pre
        __builtin_amdgcn_s_setprio(1);
        mfma_quad<0,1>(af, bf1, acc);
        __builtin_amdgcn_s_setprio(0);
        // (no P2-close: P3 stages B_q0, whose readers were synced at P1-close)

        // ---- P3: read af(mh=1); stage B_q0(k2); MFMA q(1,1)
#pragma unroll
        for (int m2 = 0; m2 < 4; ++m2) {
            const char* rb = bA + arow + (4 + m2) * 2048;
            af[m2][0] = *(const short8*)(rb + sw0);
            af[m2][1] = *(const short8*)(rb + sw1);
        }
        STG_B(p, 0, k2);
        barw();                                   // P3-pre
        __builtin_amdgcn_s_setprio(1);
        mfma_quad<1,1>(af, bf1, acc);
        __builtin_amdgcn_s_setprio(0);
        barw();                                   // P3-close (A_q1 readers synced before P4 stage)

        // ---- P4: stage B_q1+A_q1(k2); counted vmcnt; MFMA q(1,0); NO closing barrier
        STG_B(p, 1, k2);
        STG_A(p, 1, k2);
        wait_vm8();
        barw();                                   // P4-pre (next K-tile's buffer fully landed)
        __builtin_amdgcn_s_setprio(1);
        mfma_quad<1,0>(af, bf0, acc);
        __builtin_amdgcn_s_setprio(0);
        // (no P4-close: next-P1 reads other buffer, gated by P4-pre)
    }
    wait_vm0();   // drain wrapped junk stages before LDS dealloc
#undef STG_A
#undef STG_B
}

// ---------------------------------------------------------------- GEMM1 + SiLU (256x256)
__global__ __launch_bounds__(512) void gemm1_8ph(
    const unsigned short* __restrict__ xb, const unsigned short* __restrict__ w1b,
    const int* __restrict__ idxb, unsigned short* __restrict__ hbuf) {
    extern __shared__ __align__(16) char smem[];
    const int tid = threadIdx.x;
    const int blk = blockIdx.x;            // 0..1023
    const int e  = blk & 7;                // XCD id
    const int q  = blk >> 3;               // 0..127
    const int b  = q >> 5;
    const int tm = (q >> 4) & 1;
    const int tn = q & 15;
    const int g  = b * 8 + e;

    const int t8   = tid >> 3;
    const int cswz = ((tid & 7) ^ (t8 & 7)) << 4;

    const char* aS[4]; const char* bS[4];
    {
        const int ar[4] = { t8, 128 + t8, 64 + t8, 192 + t8 };   // [q*2+r]
#pragma unroll
        for (int i = 0; i < 4; ++i) {
            int tok = idxb[g * KSEL + tm * 256 + ar[i]];
            aS[i] = (const char*)xb + ((size_t)(b * S_ + tok) * D_) * 2 + cswz;
        }
        const int u = tid >> 8, v = t8 & 31;
#pragma unroll
        for (int qq = 0; qq < 2; ++qq)
#pragma unroll
            for (int r = 0; r < 2; ++r) {
                int rowb = (u + 2*r) * 64 + qq * 32 + v;
                bS[qq*2+r] = (const char*)w1b + ((size_t)(e * F_ + tn * 256 + rowb) * D_) * 2 + cswz;
            }
    }

    floatx4 acc[8][4];
#pragma unroll
    for (int m = 0; m < 8; ++m)
#pragma unroll
        for (int n = 0; n < 4; ++n) acc[m][n] = (floatx4){0.f, 0.f, 0.f, 0.f};

    mm_core<D_ / 64>(aS, bS, smem, tid, acc);   // NK = 16

    const int lane = tid & 63, wid = tid >> 6;
    const int wm = wid >> 2, wn = wid & 3;
    const int mrow = lane & 15, hi = lane >> 4;
    unsigned short* hr = hbuf + (size_t)g * ((size_t)KSEL * F_);
#pragma unroll
    for (int m = 0; m < 8; ++m) {
#pragma unroll
        for (int r2 = 0; r2 < 4; ++r2) {
            const int rowc = tm*256 + wm*128 + m*16 + hi*4 + r2;
            unsigned short* hrow = hr + (size_t)rowc * F_ + tn*256 + wn*64 + mrow;
#pragma unroll
            for (int n = 0; n < 4; ++n) {
                float v = acc[m][n][r2];
                float s = v / (1.0f + __expf(-v));
                hrow[n * 16] = f2bf(s);
            }
        }
    }
}

// ---------------------------------------------------------------- GEMM2 + gated coalesced store (256x256)
__global__ __launch_bounds__(512) void gemm2_8ph(
    const unsigned short* __restrict__ hbuf, const unsigned short* __restrict__ w2b,
    const float* __restrict__ gateb, float* __restrict__ cmb) {
    extern __shared__ __align__(16) char smem[];
    const int tid = threadIdx.x;
    const int blk = blockIdx.x;            // 0..255
    const int e  = blk & 7;
    const int q  = blk >> 3;               // 0..31
    const int b  = q >> 3;
    const int tm = (q >> 2) & 1;
    const int tn = q & 3;
    const int g  = b * 8 + e;

    const int t8   = tid >> 3;
    const int cswz = ((tid & 7) ^ (t8 & 7)) << 4;

    const char* aS[4]; const char* bS[4];
    {
        const int ar[4] = { t8, 128 + t8, 64 + t8, 192 + t8 };
#pragma unroll
        for (int i = 0; i < 4; ++i)
            aS[i] = (const char*)hbuf + ((size_t)(g * KSEL + tm * 256 + ar[i]) * F_) * 2 + cswz;
        const int u = tid >> 8, v = t8 & 31;
#pragma unroll
        for (int qq = 0; qq < 2; ++qq)
#pragma unroll
            for (int r = 0; r < 2; ++r) {
                int rowb = (u + 2*r) * 64 + qq * 32 + v;
                bS[qq*2+r] = (const char*)w2b + ((size_t)(e * D_ + tn * 256 + rowb) * F_) * 2 + cswz;
            }
    }

    floatx4 acc[8][4];
#pragma unroll
    for (int m = 0; m < 8; ++m)
#pragma unroll
        for (int n = 0; n < 4; ++n) acc[m][n] = (floatx4){0.f, 0.f, 0.f, 0.f};

    mm_core<F_ / 64>(aS, bS, smem, tid, acc);   // NK = 64

    const int lane = tid & 63, wid = tid >> 6;
    const int wm = wid >> 2, wn = wid & 3;
    const int mrow = lane & 15, hi = lane >> 4;
#pragma unroll
    for (int m = 0; m < 8; ++m) {
#pragma unroll
        for (int r2 = 0; r2 < 4; ++r2) {
            const int slot = tm*256 + wm*128 + m*16 + hi*4 + r2;
            const float gt = gateb[g * KSEL + slot];
            float* crow = cmb + ((size_t)g * KSEL + slot) * D_ + tn*256 + wn*64 + mrow;
#pragma unroll
            for (int n = 0; n < 4; ++n)
                crow[n * 16] = gt * acc[m][n][r2];
        }
    }
}

// ---------------------------------------------------------------- combine: out[b,s,:] = sum over selecting experts
__global__ void combine_kernel(const float* __restrict__ cmb,
                               const int* __restrict__ cnt,
                               const int* __restrict__ lst,
                               float* __restrict__ out) {
    const int bs = blockIdx.x;          // 0..8191  (b*S+s)
    const int tid = threadIdx.x;        // 256, float4 each -> D=1024
    const int c = cnt[bs];
    float4 acc = {0.f, 0.f, 0.f, 0.f};
    for (int i = 0; i < c; ++i) {
        const int idx = lst[bs * 8 + i];              // g*KSEL+slot
        const float4 v = ((const float4*)(cmb + (size_t)idx * D_))[tid];
        acc.x += v.x; acc.y += v.y; acc.z += v.z; acc.w += v.w;
    }
    ((float4*)(out + (size_t)bs * D_))[tid] = acc;
}

// ---------------------------------------------------------------- launch
extern "C" void kernel_launch(void* const* d_in, const int* in_sizes, int n_in,
                              void* d_out, int out_size, void* d_ws, size_t ws_size,
                              hipStream_t stream) {
    const float* x      = (const float*)d_in[0];
    const float* choice = (const float*)d_in[1];
    const float* w1     = (const float*)d_in[2];
    const float* w2     = (const float*)d_in[3];
    float* out = (float*)d_out;
    char* ws = (char*)d_ws;

    static bool inited = false;
    if (!inited) {
        hipFuncSetAttribute(reinterpret_cast<const void*>(&gemm1_8ph),
                            hipFuncAttributeMaxDynamicSharedMemorySize, 131072);
        hipFuncSetAttribute(reinterpret_cast<const void*>(&gemm2_8ph),
                            hipFuncAttributeMaxDynamicSharedMemorySize, 131072);
        inited = true;
    }

    // workspace layout (bytes)
    unsigned short* w1b = (unsigned short*)(ws);                  // 67,108,864 (reused as cmb after gemm1)
    unsigned short* w2b = (unsigned short*)(ws + 67108864);       // 67,108,864
    unsigned short* xb  = (unsigned short*)(ws + 134217728);      // 16,777,216
    unsigned short* hb  = (unsigned short*)(ws + 150994944);      // 134,217,728
    float* probs        = (float*)(ws + 285212672);               // 262,144
    int*   idxb         = (int*)(ws + 285474816);                 // 65,536
    float* gateb        = (float*)(ws + 285540352);               // 65,536
    int*   cnt          = (int*)(ws + 285605888);                 // 32,768
    int*   lst          = (int*)(ws + 285638656);                 // 262,144
    float* cmb          = (float*)(ws);                           // overlays w1b (dead after gemm1)

    convert2_kernel<<<16384, 256, 0, stream>>>(w1, w1b, w2, w2b, 8388608);
    router_kernel<<<B_ * S_, 256, 0, stream>>>(x, choice, probs, xb, cnt);
    topk_kernel<<<B_ * E_ * 8, 256, 0, stream>>>(probs, idxb, gateb, cnt, lst);
    gemm1_8ph<<<1024, 512, 131072, stream>>>(xb, w1b, idxb, hb);
    gemm2_8ph<<<256, 512, 131072, stream>>>(hb, w2b, gateb, cmb);
    combine_kernel<<<B_ * S_, 256, 0, stream>>>(cmb, cnt, lst, out);
}